// Round 6
// baseline (687.094 us; speedup 1.0000x reference)
//
#include <hip/hip_runtime.h>
#include <hip/hip_cooperative_groups.h>
#include <cstdint>

namespace cg = cooperative_groups;

#define HH 128
#define SB 136  // padded bf16 LDS row stride for GEMM A tiles (272 B: 16B-aligned, 2-way max bank alias)
constexpr int cN_X   = 250000;
constexpr int cN_SRC = 50000;
constexpr int cN_Y   = 50000;
constexpr int cN_INT = 500000;
constexpr int cE_NODE = 1000000;
constexpr int cE_DOM  = 500000;

typedef __attribute__((ext_vector_type(8))) short bf16x8;
typedef __attribute__((ext_vector_type(4))) float f32x4;

__device__ __forceinline__ float bf2f(unsigned short s) {
  union { unsigned u; float f; } v; v.u = ((unsigned)s) << 16; return v.f;
}
__device__ __forceinline__ unsigned short f2bf(float f) {
  union { float f; unsigned u; } v; v.f = f;
  unsigned r = v.u + 0x7fffu + ((v.u >> 16) & 1u);  // RNE
  return (unsigned short)(r >> 16);
}

// ---------------- MFMA helpers: self-casting fragment loader (W in f32).
// Produces byte-identical bf16 fragments to the old wcast+bf16 path (same RNE).
__device__ __forceinline__ void load_bfrags_f32(const float* __restrict__ Wf,
                                                int wv, int lane, bf16x8 bfrag[2][4]) {
  int cbase = wv * 32 + (lane & 15);
  int krow = (lane >> 4) * 8;
#pragma unroll
  for (int ct = 0; ct < 2; ct++)
#pragma unroll
    for (int kt = 0; kt < 4; kt++) {
      const float* p = Wf + (size_t)(cbase + ct * 16) * HH + kt * 32 + krow;
      float4 f0 = *(const float4*)p;
      float4 f1 = *(const float4*)(p + 4);
      bf16x8 v;
      v[0] = (short)f2bf(f0.x); v[1] = (short)f2bf(f0.y);
      v[2] = (short)f2bf(f0.z); v[3] = (short)f2bf(f0.w);
      v[4] = (short)f2bf(f1.x); v[5] = (short)f2bf(f1.y);
      v[6] = (short)f2bf(f1.z); v[7] = (short)f2bf(f1.w);
      bfrag[ct][kt] = v;
    }
}

// shared GEMM tile body: outb[row0..row0+rows][128](bf16) = A @ Wf^T
__device__ __forceinline__ void gemm_tile(const float* __restrict__ A,
                                          const float* __restrict__ Wf,
                                          unsigned short* __restrict__ outb,
                                          int row0, int rows,
                                          unsigned short* sA, int tid) {
  int lane = tid & 63, wv = tid >> 6;
  bf16x8 bfrag[2][4];
  load_bfrags_f32(Wf, wv, lane, bfrag);
#pragma unroll
  for (int it = 0; it < 4; it++) {
    int g = it * 2048 + tid * 8;
    int r = g >> 7, c = g & 127;
    bf16x8 v = {0, 0, 0, 0, 0, 0, 0, 0};
    if (r < rows) {
      float4 f0 = *(const float4*)(A + (size_t)(row0 + r) * HH + c);
      float4 f1 = *(const float4*)(A + (size_t)(row0 + r) * HH + c + 4);
      v[0] = (short)f2bf(f0.x); v[1] = (short)f2bf(f0.y);
      v[2] = (short)f2bf(f0.z); v[3] = (short)f2bf(f0.w);
      v[4] = (short)f2bf(f1.x); v[5] = (short)f2bf(f1.y);
      v[6] = (short)f2bf(f1.z); v[7] = (short)f2bf(f1.w);
    }
    *(bf16x8*)(&sA[r * SB + c]) = v;
  }
  __syncthreads();
  int m = lane & 15, q = lane >> 4;
  f32x4 acc[4][2];
#pragma unroll
  for (int rt = 0; rt < 4; rt++)
#pragma unroll
    for (int ct = 0; ct < 2; ct++) acc[rt][ct] = (f32x4){0.f, 0.f, 0.f, 0.f};
#pragma unroll
  for (int kt = 0; kt < 4; kt++) {
    int kof = kt * 32 + q * 8;
#pragma unroll
    for (int rt = 0; rt < 4; rt++) {
      bf16x8 af = *(const bf16x8*)(&sA[(rt * 16 + m) * SB + kof]);
      acc[rt][0] = __builtin_amdgcn_mfma_f32_16x16x32_bf16(af, bfrag[0][kt], acc[rt][0], 0, 0, 0);
      acc[rt][1] = __builtin_amdgcn_mfma_f32_16x16x32_bf16(af, bfrag[1][kt], acc[rt][1], 0, 0, 0);
    }
  }
  __syncthreads();
  unsigned short* sC = sA;
#pragma unroll
  for (int rt = 0; rt < 4; rt++)
#pragma unroll
    for (int ct = 0; ct < 2; ct++)
#pragma unroll
      for (int rg = 0; rg < 4; rg++) {
        int r = rt * 16 + q * 4 + rg;
        sC[r * HH + wv * 32 + ct * 16 + m] = f2bf(acc[rt][ct][rg]);
      }
  __syncthreads();
  for (int i = tid; i < rows * 16; i += 256) {
    int r = i >> 4, g = i & 15;
    ((uint4*)(outb + (size_t)(row0 + r) * HH))[g] = ((const uint4*)(sC + r * HH))[g];
  }
}

// ---------------- setup mega-kernel: ylin GEMM + zero(xsum,cnt,part2) + bounds.
// All regions mutually independent; consumers are in LATER dispatches.
// blocks: [0,782) ylin gemm | [782,7032) zero xsum | [7032,7081) zero cnt |
//         [7081,7097) zero part2 | [7097,11004) bounds
__global__ __launch_bounds__(256) void k_setup(const float* __restrict__ y,
                                               const float* __restrict__ Wy,
                                               unsigned short* __restrict__ ylin,
                                               const int* __restrict__ ii,
                                               int* __restrict__ bnd,
                                               float* __restrict__ xsum,
                                               int* __restrict__ cnt,
                                               float* __restrict__ part2) {
  __shared__ unsigned short sA[64 * SB];
  int b = blockIdx.x, tid = threadIdx.x;
  if (b < 782) {  // ylin = y @ Wy^T (self-cast Wy)
    int row0 = b * 64;
    int rows = min(64, cN_Y - row0);
    gemm_tile(y, Wy, ylin, row0, rows, sA, tid);
    return;
  }
  b -= 782;
  if (b < 6250) {  // zero xsum: 6.4M floats = 1.6M float4
    ((float4*)xsum)[(size_t)b * 256 + tid] = make_float4(0.f, 0.f, 0.f, 0.f);
    return;
  }
  b -= 6250;
  if (b < 49) {  // zero cnt: 50000 ints = 12500 int4
    int i = b * 256 + tid;
    if (i < 12500) ((int4*)cnt)[i] = make_int4(0, 0, 0, 0);
    return;
  }
  b -= 49;
  if (b < 16) {  // zero part2: 16384 floats = 4096 float4
    ((float4*)part2)[b * 256 + tid] = make_float4(0.f, 0.f, 0.f, 0.f);
    return;
  }
  b -= 16;
  {  // bounds: bnd[e] = first j with ii[j] >= e
    int j = b * 256 + tid;
    if (j > cE_NODE) return;
    if (j == cE_NODE) {
      int a = ii[cE_NODE - 1];
      for (int e = a + 1; e <= cN_INT; ++e) bnd[e] = cE_NODE;
      return;
    }
    int bb = ii[j];
    int a = (j == 0) ? -1 : ii[j - 1];
    for (int e = a + 1; e <= bb; ++e) bnd[e] = j;
  }
}

// ---------------- fused: xw = x @ Wxint^T (self-cast) + segsum(x) + dme1 hist.
__global__ __launch_bounds__(256, 4) void k_gemmx_segsum(
    const float* __restrict__ A, const int* __restrict__ ind,
    const float* __restrict__ Wxint,
    unsigned short* __restrict__ outb, float* __restrict__ xsum,
    const int* __restrict__ dme1, int* __restrict__ cnt) {
  __shared__ unsigned short sA[64 * SB];
  __shared__ int sind[64];
  int tid = threadIdx.x, lane = tid & 63, wv = tid >> 6;
  {  // fused histogram of dme1 (grid 3907 x 256 covers 500K with guard)
    int e = blockIdx.x * 256 + tid;
    if (e < cE_DOM) atomicAdd(&cnt[dme1[e]], 1);
  }
  int row0 = blockIdx.x * 64;
  int rows = min(64, cN_X - row0);
  if (tid < 64 && tid < rows) sind[tid] = ind[row0 + tid];
  bf16x8 bfrag[2][4];
  load_bfrags_f32(Wxint, wv, lane, bfrag);
  // stage 64x128 f32 -> bf16 LDS
#pragma unroll
  for (int it = 0; it < 4; it++) {
    int g = it * 2048 + tid * 8;
    int r = g >> 7, c = g & 127;
    bf16x8 v = {0, 0, 0, 0, 0, 0, 0, 0};
    if (r < rows) {
      float4 f0 = *(const float4*)(A + (size_t)(row0 + r) * HH + c);
      float4 f1 = *(const float4*)(A + (size_t)(row0 + r) * HH + c + 4);
      v[0] = (short)f2bf(f0.x); v[1] = (short)f2bf(f0.y);
      v[2] = (short)f2bf(f0.z); v[3] = (short)f2bf(f0.w);
      v[4] = (short)f2bf(f1.x); v[5] = (short)f2bf(f1.y);
      v[6] = (short)f2bf(f1.z); v[7] = (short)f2bf(f1.w);
    }
    *(bf16x8*)(&sA[r * SB + c]) = v;
  }
  __syncthreads();
  // ---- segment-sum side: wave wv owns rows [wv*16, wv*16+16), lane = col pair
  {
    int rbase = wv * 16;
    if (rbase < rows) {
      int nr = min(16, rows - rbase);
      int c0 = lane * 2;
      unsigned xv[16];
#pragma unroll
      for (int k = 0; k < 16; k++)
        xv[k] = (k < nr) ? *(const unsigned*)(&sA[(rbase + k) * SB + c0]) : 0u;
      float a0 = 0.f, a1 = 0.f;
      int cur = sind[rbase];
      bool inside = false;
#pragma unroll
      for (int k = 0; k < 16; k++) {
        if (k < nr) {
          int s = sind[rbase + k];
          if (s != cur) {
            if (inside) {
              xsum[(size_t)cur * HH + c0] = a0;
              xsum[(size_t)cur * HH + c0 + 1] = a1;
            } else {
              atomicAdd(&xsum[(size_t)cur * HH + c0], a0);
              atomicAdd(&xsum[(size_t)cur * HH + c0 + 1], a1);
            }
            cur = s; a0 = 0.f; a1 = 0.f; inside = true;
          }
          a0 += bf2f(xv[k] & 0xffff); a1 += bf2f(xv[k] >> 16);
        }
      }
      atomicAdd(&xsum[(size_t)cur * HH + c0], a0);
      atomicAdd(&xsum[(size_t)cur * HH + c0 + 1], a1);
    }
  }
  // ---- MFMA side
  int m = lane & 15, q = lane >> 4;
  f32x4 acc[4][2];
#pragma unroll
  for (int rt = 0; rt < 4; rt++)
#pragma unroll
    for (int ct = 0; ct < 2; ct++) acc[rt][ct] = (f32x4){0.f, 0.f, 0.f, 0.f};
#pragma unroll
  for (int kt = 0; kt < 4; kt++) {
    int kof = kt * 32 + q * 8;
#pragma unroll
    for (int rt = 0; rt < 4; rt++) {
      bf16x8 af = *(const bf16x8*)(&sA[(rt * 16 + m) * SB + kof]);
      acc[rt][0] = __builtin_amdgcn_mfma_f32_16x16x32_bf16(af, bfrag[0][kt], acc[rt][0], 0, 0, 0);
      acc[rt][1] = __builtin_amdgcn_mfma_f32_16x16x32_bf16(af, bfrag[1][kt], acc[rt][1], 0, 0, 0);
    }
  }
  __syncthreads();
  unsigned short* sC = sA;
#pragma unroll
  for (int rt = 0; rt < 4; rt++)
#pragma unroll
    for (int ct = 0; ct < 2; ct++)
#pragma unroll
      for (int rg = 0; rg < 4; rg++) {
        int r = rt * 16 + q * 4 + rg;
        sC[r * HH + wv * 32 + ct * 16 + m] = f2bf(acc[rt][ct][rg]);
      }
  __syncthreads();
  for (int i = tid; i < rows * 16; i += 256) {
    int r = i >> 4, g = i & 15;
    ((uint4*)(outb + (size_t)(row0 + r) * HH))[g] = ((const uint4*)(sC + r * HH))[g];
  }
}

// ---------------- xsl = xsum @ Wxsum^T (self-cast), 782 blocks
__global__ __launch_bounds__(256, 4) void k_gemmxsl(const float* __restrict__ xsum,
                                                    const float* __restrict__ Wxsum,
                                                    unsigned short* __restrict__ xsl) {
  __shared__ unsigned short sA[64 * SB];
  int row0 = blockIdx.x * 64;
  int rows = min(64, cN_SRC - row0);
  gemm_tile(xsum, Wxsum, xsl, row0, rows, sA, threadIdx.x);
}

// ---------------- cooperative CSR build: scan1 + scan23 + scatter in one
// kernel with grid.sync. 1024 blocks x 256 thr = 4 blocks/CU co-resident.
__global__ __launch_bounds__(256, 4) void k_csr(const int* __restrict__ cnt,
                                                int* __restrict__ bsum,
                                                int* __restrict__ excl,
                                                int* __restrict__ offs,
                                                int* __restrict__ cursor,
                                                const int* __restrict__ dme0,
                                                const int* __restrict__ dme1,
                                                const int* __restrict__ bnd,
                                                int4* __restrict__ rec) {
  cg::grid_group grid = cg::this_grid();
  __shared__ int buf[256];
  __shared__ int ex[256];
  const int nb = (cN_SRC + 255) / 256;  // 196
  int tid = threadIdx.x;
  // ---- phase 1: per-chunk inclusive scan (chunk = blockIdx.x < nb)
  if (blockIdx.x < nb) {
    int i = blockIdx.x * 256 + tid;
    int v = (i < cN_SRC) ? cnt[i] : 0;
    buf[tid] = v; __syncthreads();
    for (int d = 1; d < 256; d <<= 1) {
      int t = (tid >= d) ? buf[tid - d] : 0;
      __syncthreads();
      buf[tid] += t;
      __syncthreads();
    }
    if (i < cN_SRC) excl[i] = buf[tid] - v;
    if (tid == 255) bsum[blockIdx.x] = buf[255];
  }
  grid.sync();
  // ---- phase 2: every block redundantly scans bsum; chunk blockIdx applies
  {
    int v = (tid < nb) ? bsum[tid] : 0;
    buf[tid] = v; __syncthreads();
    for (int d = 1; d < 256; d <<= 1) {
      int t = (tid >= d) ? buf[tid - d] : 0;
      __syncthreads();
      buf[tid] += t;
      __syncthreads();
    }
    ex[tid] = buf[tid] - v;
    __syncthreads();
    int i = blockIdx.x * 256 + tid;
    if (i < cN_SRC) { int o = excl[i] + ex[i >> 8]; offs[i] = o; cursor[i] = o; }
    else if (i == cN_SRC) offs[cN_SRC] = cE_DOM;
  }
  grid.sync();
  // ---- phase 3: scatter metadata records to CSR positions (grid-stride)
  for (int e = blockIdx.x * 256 + tid; e < cE_DOM; e += gridDim.x * 256) {
    int t = dme1[e];
    int pos = atomicAdd(&cursor[t], 1);
    int j0 = bnd[e];
    rec[pos] = make_int4(dme0[e], t, j0, bnd[e + 1] - j0);
  }
}

// ---------------- edge kernel (unchanged, verified)
#define EDGE_ISSUE(I, B)                                                     \
  do {                                                                       \
    int le_ = wv * 8 + (I);                                                  \
    int n_ = __builtin_amdgcn_readfirstlane(sR[le_].w);                      \
    _Pragma("unroll")                                                        \
    for (int k_ = 0; k_ < 4; k_++) {                                         \
      int r_ = (k_ < n_) ? __builtin_amdgcn_readlane(idxv[I], k_) : 0;       \
      ub[B][k_] = xwu[(size_t)r_ * 64 + lane];                               \
    }                                                                        \
  } while (0)

#define EDGE_CONSUME(I, B)                                                   \
  do {                                                                       \
    int le_ = wv * 8 + (I);                                                  \
    int j0_ = __builtin_amdgcn_readfirstlane(sR[le_].z);                     \
    int n_ = __builtin_amdgcn_readfirstlane(sR[le_].w);                      \
    float a0_ = 0.f, a1_ = 0.f;                                              \
    _Pragma("unroll")                                                        \
    for (int k_ = 0; k_ < 4; k_++) {                                         \
      unsigned uv_ = (k_ < n_) ? ub[B][k_] : 0u;                             \
      a0_ += bf2f(uv_ & 0xffff);                                             \
      a1_ += bf2f(uv_ >> 16);                                                \
    }                                                                        \
    if (n_ > 4) {                                                            \
      for (int k_ = 4; k_ < n_; k_++) {                                      \
        int r_ = (k_ < 64) ? __builtin_amdgcn_readlane(idxv[I], k_)          \
                           : nme0[j0_ + k_];                                 \
        unsigned uu_ = xwu[(size_t)r_ * 64 + lane];                          \
        a0_ += bf2f(uu_ & 0xffff);                                           \
        a1_ += bf2f(uu_ >> 16);                                              \
      }                                                                      \
    }                                                                        \
    float m0_ = a0_ + bf2f(xs[I] & 0xffff) + bf2f(yy[I] & 0xffff);           \
    float m1_ = a1_ + bf2f(xs[I] >> 16) + bf2f(yy[I] >> 16);                 \
    unsigned um_ = ((unsigned)f2bf(m1_) << 16) | (unsigned)f2bf(m0_);        \
    __builtin_nontemporal_store(um_, &msgu[(size_t)(e0 + le_) * 64 + lane]); \
    s0 += m0_; q0 += m0_ * m0_; s1 += m1_; q1 += m1_ * m1_;                  \
  } while (0)

#define SBAR __builtin_amdgcn_sched_barrier(0)

__global__ __launch_bounds__(256, 8) void k_edge2(
    const unsigned* __restrict__ xwu, const int* __restrict__ nme0,
    const unsigned* __restrict__ xslu, const unsigned* __restrict__ ylu,
    const int4* __restrict__ rec,
    unsigned* __restrict__ msgu, float* __restrict__ part2) {
  __shared__ int4 sR[32];
  __shared__ float sBN[1024];
  int tid = threadIdx.x, lane = tid & 63, wv = tid >> 6;
  int e0 = blockIdx.x * 32;
  if (tid < 32) sR[tid] = rec[e0 + tid];
  __syncthreads();

  unsigned xs[8], yy[8];
  int idxv[8];
#pragma unroll
  for (int i = 0; i < 8; i++) {
    int le = wv * 8 + i;
    int s  = __builtin_amdgcn_readfirstlane(sR[le].x);
    int t  = __builtin_amdgcn_readfirstlane(sR[le].y);
    int j0 = __builtin_amdgcn_readfirstlane(sR[le].z);
    int n  = __builtin_amdgcn_readfirstlane(sR[le].w);
    xs[i] = xslu[(size_t)s * 64 + lane];
    yy[i] = ylu[(size_t)t * 64 + lane];
    idxv[i] = (lane < n) ? nme0[j0 + lane] : 0;
  }
  SBAR;

  float s0 = 0.f, q0 = 0.f, s1 = 0.f, q1 = 0.f;
  unsigned ub[3][4];
  EDGE_ISSUE(0, 0); SBAR;
  EDGE_ISSUE(1, 1); SBAR;
  EDGE_ISSUE(2, 2); SBAR;
  EDGE_CONSUME(0, 0);
  EDGE_ISSUE(3, 0); SBAR;
  EDGE_CONSUME(1, 1);
  EDGE_ISSUE(4, 1); SBAR;
  EDGE_CONSUME(2, 2);
  EDGE_ISSUE(5, 2); SBAR;
  EDGE_CONSUME(3, 0);
  EDGE_ISSUE(6, 0); SBAR;
  EDGE_CONSUME(4, 1);
  EDGE_ISSUE(7, 1); SBAR;
  EDGE_CONSUME(5, 2);
  EDGE_CONSUME(6, 0);
  EDGE_CONSUME(7, 1);

  *(float4*)(&sBN[wv * 256 + lane * 4]) = make_float4(s0, q0, s1, q1);
  __syncthreads();
  float v = sBN[tid] + sBN[256 + tid] + sBN[512 + tid] + sBN[768 + tid];
  atomicAdd(&part2[((blockIdx.x & 63) << 8) + tid], v);
}

// ---------------- BN stat finalize
__global__ __launch_bounds__(256) void k_bnfinal(const float* __restrict__ part2,
                                                 const float* __restrict__ bnw,
                                                 const float* __restrict__ bnb,
                                                 float* __restrict__ ss) {
  __shared__ float L[256];
  float s = 0.f;
  for (int b = 0; b < 64; b++) s += part2[b * 256 + threadIdx.x];
  L[threadIdx.x] = s; __syncthreads();
  if (threadIdx.x < HH) {
    int c = threadIdx.x;
    float sum = L[2 * c], sq = L[2 * c + 1];
    float mean = sum / (float)cE_DOM;
    float var = sq / (float)cE_DOM - mean * mean;
    float sc = bnw[c] * rsqrtf(var + 1e-5f);
    float sh = bnb[c] - mean * sc;
    ss[2 * c] = sc; ss[2 * c + 1] = sh;
  }
}

// ---------------- final reduce (unchanged)
__global__ __launch_bounds__(256, 8) void k_out2(const unsigned* __restrict__ msgu,
                                                 const int* __restrict__ offs,
                                                 const float* __restrict__ ss,
                                                 float* __restrict__ out) {
  int wv = threadIdx.x >> 6, lane = threadIdx.x & 63;
  int t = blockIdx.x * 4 + wv;
  if (t >= cN_Y) return;
  int c0 = lane * 2;
  float sc0 = ss[c0 * 2 + 0], sh0 = ss[c0 * 2 + 1];
  float sc1 = ss[c0 * 2 + 2], sh1 = ss[c0 * 2 + 3];
  int j0 = __builtin_amdgcn_readfirstlane(offs[t]);
  int j1 = __builtin_amdgcn_readfirstlane(offs[t + 1]);
  float a0 = 0.f, a1 = 0.f;
  int p = j0;
  for (; p + 8 <= j1; p += 8) {
    unsigned m[8];
#pragma unroll
    for (int k = 0; k < 8; k++) m[k] = msgu[(size_t)(p + k) * 64 + lane];
    __builtin_amdgcn_sched_barrier(0);
#pragma unroll
    for (int k = 0; k < 8; k++) {
      a0 += fmaxf(fmaf(bf2f(m[k] & 0xffff), sc0, sh0), 0.f);
      a1 += fmaxf(fmaf(bf2f(m[k] >> 16), sc1, sh1), 0.f);
    }
  }
  if (p + 4 <= j1) {
    unsigned m[4];
#pragma unroll
    for (int k = 0; k < 4; k++) m[k] = msgu[(size_t)(p + k) * 64 + lane];
    __builtin_amdgcn_sched_barrier(0);
#pragma unroll
    for (int k = 0; k < 4; k++) {
      a0 += fmaxf(fmaf(bf2f(m[k] & 0xffff), sc0, sh0), 0.f);
      a1 += fmaxf(fmaf(bf2f(m[k] >> 16), sc1, sh1), 0.f);
    }
    p += 4;
  }
  for (; p < j1; p++) {
    unsigned m = msgu[(size_t)p * 64 + lane];
    a0 += fmaxf(fmaf(bf2f(m & 0xffff), sc0, sh0), 0.f);
    a1 += fmaxf(fmaf(bf2f(m >> 16), sc1, sh1), 0.f);
  }
  *(float2*)(out + (size_t)t * HH + c0) = make_float2(a0, a1);
}

extern "C" void kernel_launch(void* const* d_in, const int* in_sizes, int n_in,
                              void* d_out, int out_size, void* d_ws, size_t ws_size,
                              hipStream_t stream) {
  const float* x     = (const float*)d_in[0];
  const float* y     = (const float*)d_in[1];
  const int* dom_ind = (const int*)d_in[2];
  const int* nme     = (const int*)d_in[3];
  const int* ii      = (const int*)d_in[4];
  const int* dme     = (const int*)d_in[5];
  const float* Wxsum = (const float*)d_in[6];
  const float* Wxint = (const float*)d_in[7];
  const float* Wy    = (const float*)d_in[8];
  const float* bnw   = (const float*)d_in[9];
  const float* bnb   = (const float*)d_in[10];
  float* out = (float*)d_out;

  char* ws = (char*)d_ws;
  size_t o = 0;
  auto alloc = [&](size_t bytes) -> void* {
    void* p = ws + o;
    o = (o + bytes + 255) & ~(size_t)255;
    return p;
  };
  float* xsum   = (float*)alloc((size_t)cN_SRC * HH * 4);
  unsigned short* xsl = (unsigned short*)alloc((size_t)cN_SRC * HH * 2);
  unsigned short* ylin = (unsigned short*)alloc((size_t)cN_Y * HH * 2);
  unsigned short* xw = (unsigned short*)alloc((size_t)cN_X * HH * 2);
  unsigned short* msg = (unsigned short*)alloc((size_t)cE_DOM * HH * 2);
  int* bnd      = (int*)alloc((size_t)(cN_INT + 1) * 4);
  int* cnt      = (int*)alloc((size_t)cN_SRC * 4);
  int* excl     = (int*)alloc((size_t)cN_SRC * 4);
  int* bsum     = (int*)alloc(256 * 4);
  int* offs     = (int*)alloc((size_t)(cN_SRC + 1) * 4);
  int* cursor   = (int*)alloc((size_t)cN_SRC * 4);
  int4* rec     = (int4*)alloc((size_t)cE_DOM * 16);
  float* part2  = (float*)alloc(64 * 256 * 4);
  float* ssbuf  = (float*)alloc(256 * 4);

  // setup: 782 ylin-gemm + 6250 zero-xsum + 49 zero-cnt + 16 zero-part2 + 3907 bounds
  k_setup<<<782 + 6250 + 49 + 16 + 3907, 256, 0, stream>>>(y, Wy, ylin, ii, bnd,
                                                           xsum, cnt, part2);
  k_gemmx_segsum<<<(cN_X + 63) / 64, 256, 0, stream>>>(x, dom_ind, Wxint, xw, xsum,
                                                       dme + cE_DOM, cnt);
  k_gemmxsl<<<(cN_SRC + 63) / 64, 256, 0, stream>>>(xsum, Wxsum, xsl);
  {
    const int* dme0p = dme;
    const int* dme1p = dme + cE_DOM;
    void* csrArgs[] = {(void*)&cnt, (void*)&bsum, (void*)&excl, (void*)&offs,
                       (void*)&cursor, (void*)&dme0p, (void*)&dme1p,
                       (void*)&bnd, (void*)&rec};
    hipLaunchCooperativeKernel((const void*)k_csr, dim3(1024), dim3(256),
                               csrArgs, 0, stream);
  }
  k_edge2<<<cE_DOM / 32, 256, 0, stream>>>((const unsigned*)xw, nme,
                                           (const unsigned*)xsl, (const unsigned*)ylin,
                                           rec, (unsigned*)msg, part2);
  k_bnfinal<<<1, 256, 0, stream>>>(part2, bnw, bnb, ssbuf);
  k_out2<<<(cN_Y + 3) / 4, 256, 0, stream>>>((const unsigned*)msg, offs, ssbuf, out);
}

// Round 7
// 442.001 us; speedup vs baseline: 1.5545x; 1.5545x over previous
//
#include <hip/hip_runtime.h>
#include <cstdint>

#define HH 128
#define SB 136  // padded bf16 LDS row stride for GEMM A tiles (272 B: 16B-aligned, 2-way max bank alias)
constexpr int cN_X   = 250000;
constexpr int cN_SRC = 50000;
constexpr int cN_Y   = 50000;
constexpr int cN_INT = 500000;
constexpr int cE_NODE = 1000000;
constexpr int cE_DOM  = 500000;

typedef __attribute__((ext_vector_type(8))) short bf16x8;
typedef __attribute__((ext_vector_type(4))) float f32x4;

__device__ __forceinline__ float bf2f(unsigned short s) {
  union { unsigned u; float f; } v; v.u = ((unsigned)s) << 16; return v.f;
}
__device__ __forceinline__ unsigned short f2bf(float f) {
  union { float f; unsigned u; } v; v.f = f;
  unsigned r = v.u + 0x7fffu + ((v.u >> 16) & 1u);  // RNE
  return (unsigned short)(r >> 16);
}

// ---------------- MFMA helpers: self-casting fragment loader (W in f32).
// Produces byte-identical bf16 fragments to the old wcast+bf16 path (same RNE).
__device__ __forceinline__ void load_bfrags_f32(const float* __restrict__ Wf,
                                                int wv, int lane, bf16x8 bfrag[2][4]) {
  int cbase = wv * 32 + (lane & 15);
  int krow = (lane >> 4) * 8;
#pragma unroll
  for (int ct = 0; ct < 2; ct++)
#pragma unroll
    for (int kt = 0; kt < 4; kt++) {
      const float* p = Wf + (size_t)(cbase + ct * 16) * HH + kt * 32 + krow;
      float4 f0 = *(const float4*)p;
      float4 f1 = *(const float4*)(p + 4);
      bf16x8 v;
      v[0] = (short)f2bf(f0.x); v[1] = (short)f2bf(f0.y);
      v[2] = (short)f2bf(f0.z); v[3] = (short)f2bf(f0.w);
      v[4] = (short)f2bf(f1.x); v[5] = (short)f2bf(f1.y);
      v[6] = (short)f2bf(f1.z); v[7] = (short)f2bf(f1.w);
      bfrag[ct][kt] = v;
    }
}

// shared GEMM tile body: outb[row0..row0+rows][128](bf16) = A @ Wf^T
__device__ __forceinline__ void gemm_tile(const float* __restrict__ A,
                                          const float* __restrict__ Wf,
                                          unsigned short* __restrict__ outb,
                                          int row0, int rows,
                                          unsigned short* sA, int tid) {
  int lane = tid & 63, wv = tid >> 6;
  bf16x8 bfrag[2][4];
  load_bfrags_f32(Wf, wv, lane, bfrag);
#pragma unroll
  for (int it = 0; it < 4; it++) {
    int g = it * 2048 + tid * 8;
    int r = g >> 7, c = g & 127;
    bf16x8 v = {0, 0, 0, 0, 0, 0, 0, 0};
    if (r < rows) {
      float4 f0 = *(const float4*)(A + (size_t)(row0 + r) * HH + c);
      float4 f1 = *(const float4*)(A + (size_t)(row0 + r) * HH + c + 4);
      v[0] = (short)f2bf(f0.x); v[1] = (short)f2bf(f0.y);
      v[2] = (short)f2bf(f0.z); v[3] = (short)f2bf(f0.w);
      v[4] = (short)f2bf(f1.x); v[5] = (short)f2bf(f1.y);
      v[6] = (short)f2bf(f1.z); v[7] = (short)f2bf(f1.w);
    }
    *(bf16x8*)(&sA[r * SB + c]) = v;
  }
  __syncthreads();
  int m = lane & 15, q = lane >> 4;
  f32x4 acc[4][2];
#pragma unroll
  for (int rt = 0; rt < 4; rt++)
#pragma unroll
    for (int ct = 0; ct < 2; ct++) acc[rt][ct] = (f32x4){0.f, 0.f, 0.f, 0.f};
#pragma unroll
  for (int kt = 0; kt < 4; kt++) {
    int kof = kt * 32 + q * 8;
#pragma unroll
    for (int rt = 0; rt < 4; rt++) {
      bf16x8 af = *(const bf16x8*)(&sA[(rt * 16 + m) * SB + kof]);
      acc[rt][0] = __builtin_amdgcn_mfma_f32_16x16x32_bf16(af, bfrag[0][kt], acc[rt][0], 0, 0, 0);
      acc[rt][1] = __builtin_amdgcn_mfma_f32_16x16x32_bf16(af, bfrag[1][kt], acc[rt][1], 0, 0, 0);
    }
  }
  __syncthreads();
  unsigned short* sC = sA;
#pragma unroll
  for (int rt = 0; rt < 4; rt++)
#pragma unroll
    for (int ct = 0; ct < 2; ct++)
#pragma unroll
      for (int rg = 0; rg < 4; rg++) {
        int r = rt * 16 + q * 4 + rg;
        sC[r * HH + wv * 32 + ct * 16 + m] = f2bf(acc[rt][ct][rg]);
      }
  __syncthreads();
  for (int i = tid; i < rows * 16; i += 256) {
    int r = i >> 4, g = i & 15;
    ((uint4*)(outb + (size_t)(row0 + r) * HH))[g] = ((const uint4*)(sC + r * HH))[g];
  }
}

// ---------------- setup mega-kernel: ylin GEMM + zero(xsum,cnt,part2) + bounds.
// All regions mutually independent; consumers are in LATER dispatches.
// blocks: [0,782) ylin gemm | [782,7032) zero xsum | [7032,7081) zero cnt |
//         [7081,7097) zero part2 | [7097,11004) bounds
__global__ __launch_bounds__(256) void k_setup(const float* __restrict__ y,
                                               const float* __restrict__ Wy,
                                               unsigned short* __restrict__ ylin,
                                               const int* __restrict__ ii,
                                               int* __restrict__ bnd,
                                               float* __restrict__ xsum,
                                               int* __restrict__ cnt,
                                               float* __restrict__ part2) {
  __shared__ unsigned short sA[64 * SB];
  int b = blockIdx.x, tid = threadIdx.x;
  if (b < 782) {  // ylin = y @ Wy^T (self-cast Wy)
    int row0 = b * 64;
    int rows = min(64, cN_Y - row0);
    gemm_tile(y, Wy, ylin, row0, rows, sA, tid);
    return;
  }
  b -= 782;
  if (b < 6250) {  // zero xsum: 6.4M floats = 1.6M float4
    ((float4*)xsum)[(size_t)b * 256 + tid] = make_float4(0.f, 0.f, 0.f, 0.f);
    return;
  }
  b -= 6250;
  if (b < 49) {  // zero cnt: 50000 ints = 12500 int4
    int i = b * 256 + tid;
    if (i < 12500) ((int4*)cnt)[i] = make_int4(0, 0, 0, 0);
    return;
  }
  b -= 49;
  if (b < 16) {  // zero part2: 16384 floats = 4096 float4
    ((float4*)part2)[b * 256 + tid] = make_float4(0.f, 0.f, 0.f, 0.f);
    return;
  }
  b -= 16;
  {  // bounds: bnd[e] = first j with ii[j] >= e
    int j = b * 256 + tid;
    if (j > cE_NODE) return;
    if (j == cE_NODE) {
      int a = ii[cE_NODE - 1];
      for (int e = a + 1; e <= cN_INT; ++e) bnd[e] = cE_NODE;
      return;
    }
    int bb = ii[j];
    int a = (j == 0) ? -1 : ii[j - 1];
    for (int e = a + 1; e <= bb; ++e) bnd[e] = j;
  }
}

// ---------------- fused: xw = x @ Wxint^T (self-cast) + segsum(x) + dme1 hist.
__global__ __launch_bounds__(256, 4) void k_gemmx_segsum(
    const float* __restrict__ A, const int* __restrict__ ind,
    const float* __restrict__ Wxint,
    unsigned short* __restrict__ outb, float* __restrict__ xsum,
    const int* __restrict__ dme1, int* __restrict__ cnt) {
  __shared__ unsigned short sA[64 * SB];
  __shared__ int sind[64];
  int tid = threadIdx.x, lane = tid & 63, wv = tid >> 6;
  {  // fused histogram of dme1 (grid 3907 x 256 covers 500K with guard)
    int e = blockIdx.x * 256 + tid;
    if (e < cE_DOM) atomicAdd(&cnt[dme1[e]], 1);
  }
  int row0 = blockIdx.x * 64;
  int rows = min(64, cN_X - row0);
  if (tid < 64 && tid < rows) sind[tid] = ind[row0 + tid];
  bf16x8 bfrag[2][4];
  load_bfrags_f32(Wxint, wv, lane, bfrag);
  // stage 64x128 f32 -> bf16 LDS
#pragma unroll
  for (int it = 0; it < 4; it++) {
    int g = it * 2048 + tid * 8;
    int r = g >> 7, c = g & 127;
    bf16x8 v = {0, 0, 0, 0, 0, 0, 0, 0};
    if (r < rows) {
      float4 f0 = *(const float4*)(A + (size_t)(row0 + r) * HH + c);
      float4 f1 = *(const float4*)(A + (size_t)(row0 + r) * HH + c + 4);
      v[0] = (short)f2bf(f0.x); v[1] = (short)f2bf(f0.y);
      v[2] = (short)f2bf(f0.z); v[3] = (short)f2bf(f0.w);
      v[4] = (short)f2bf(f1.x); v[5] = (short)f2bf(f1.y);
      v[6] = (short)f2bf(f1.z); v[7] = (short)f2bf(f1.w);
    }
    *(bf16x8*)(&sA[r * SB + c]) = v;
  }
  __syncthreads();
  // ---- segment-sum side: wave wv owns rows [wv*16, wv*16+16), lane = col pair
  {
    int rbase = wv * 16;
    if (rbase < rows) {
      int nr = min(16, rows - rbase);
      int c0 = lane * 2;
      unsigned xv[16];
#pragma unroll
      for (int k = 0; k < 16; k++)
        xv[k] = (k < nr) ? *(const unsigned*)(&sA[(rbase + k) * SB + c0]) : 0u;
      float a0 = 0.f, a1 = 0.f;
      int cur = sind[rbase];
      bool inside = false;
#pragma unroll
      for (int k = 0; k < 16; k++) {
        if (k < nr) {
          int s = sind[rbase + k];
          if (s != cur) {
            if (inside) {
              xsum[(size_t)cur * HH + c0] = a0;
              xsum[(size_t)cur * HH + c0 + 1] = a1;
            } else {
              atomicAdd(&xsum[(size_t)cur * HH + c0], a0);
              atomicAdd(&xsum[(size_t)cur * HH + c0 + 1], a1);
            }
            cur = s; a0 = 0.f; a1 = 0.f; inside = true;
          }
          a0 += bf2f(xv[k] & 0xffff); a1 += bf2f(xv[k] >> 16);
        }
      }
      atomicAdd(&xsum[(size_t)cur * HH + c0], a0);
      atomicAdd(&xsum[(size_t)cur * HH + c0 + 1], a1);
    }
  }
  // ---- MFMA side
  int m = lane & 15, q = lane >> 4;
  f32x4 acc[4][2];
#pragma unroll
  for (int rt = 0; rt < 4; rt++)
#pragma unroll
    for (int ct = 0; ct < 2; ct++) acc[rt][ct] = (f32x4){0.f, 0.f, 0.f, 0.f};
#pragma unroll
  for (int kt = 0; kt < 4; kt++) {
    int kof = kt * 32 + q * 8;
#pragma unroll
    for (int rt = 0; rt < 4; rt++) {
      bf16x8 af = *(const bf16x8*)(&sA[(rt * 16 + m) * SB + kof]);
      acc[rt][0] = __builtin_amdgcn_mfma_f32_16x16x32_bf16(af, bfrag[0][kt], acc[rt][0], 0, 0, 0);
      acc[rt][1] = __builtin_amdgcn_mfma_f32_16x16x32_bf16(af, bfrag[1][kt], acc[rt][1], 0, 0, 0);
    }
  }
  __syncthreads();
  unsigned short* sC = sA;
#pragma unroll
  for (int rt = 0; rt < 4; rt++)
#pragma unroll
    for (int ct = 0; ct < 2; ct++)
#pragma unroll
      for (int rg = 0; rg < 4; rg++) {
        int r = rt * 16 + q * 4 + rg;
        sC[r * HH + wv * 32 + ct * 16 + m] = f2bf(acc[rt][ct][rg]);
      }
  __syncthreads();
  for (int i = tid; i < rows * 16; i += 256) {
    int r = i >> 4, g = i & 15;
    ((uint4*)(outb + (size_t)(row0 + r) * HH))[g] = ((const uint4*)(sC + r * HH))[g];
  }
}

// ---------------- xsl = xsum @ Wxsum^T (self-cast), 782 blocks
__global__ __launch_bounds__(256, 4) void k_gemmxsl(const float* __restrict__ xsum,
                                                    const float* __restrict__ Wxsum,
                                                    unsigned short* __restrict__ xsl) {
  __shared__ unsigned short sA[64 * SB];
  int row0 = blockIdx.x * 64;
  int rows = min(64, cN_SRC - row0);
  gemm_tile(xsum, Wxsum, xsl, row0, rows, sA, threadIdx.x);
}

// ---------------- CSR build (plain launches; cooperative grid.sync was a
// 254 us regression -- round-6 post-mortem)
__global__ __launch_bounds__(256) void k_scan1(const int* __restrict__ cnt,
                                               int* __restrict__ bsum, int* __restrict__ excl) {
  __shared__ int buf[256];
  int i = blockIdx.x * 256 + threadIdx.x;
  int v = (i < cN_SRC) ? cnt[i] : 0;
  buf[threadIdx.x] = v; __syncthreads();
  for (int d = 1; d < 256; d <<= 1) {
    int t = (threadIdx.x >= d) ? buf[threadIdx.x - d] : 0;
    __syncthreads();
    buf[threadIdx.x] += t;
    __syncthreads();
  }
  if (i < cN_SRC) excl[i] = buf[threadIdx.x] - v;
  if (threadIdx.x == 255) bsum[blockIdx.x] = buf[255];
}
// scan2+scan3 fused: every block redundantly scans the 196 block sums
__global__ __launch_bounds__(256) void k_scan23(const int* __restrict__ excl,
                                                const int* __restrict__ bsum,
                                                int* __restrict__ offs,
                                                int* __restrict__ cursor, int nb) {
  __shared__ int buf[256];
  __shared__ int ex[256];
  int tid = threadIdx.x;
  int v = (tid < nb) ? bsum[tid] : 0;
  buf[tid] = v; __syncthreads();
  for (int d = 1; d < 256; d <<= 1) {
    int t = (tid >= d) ? buf[tid - d] : 0;
    __syncthreads();
    buf[tid] += t;
    __syncthreads();
  }
  ex[tid] = buf[tid] - v;
  __syncthreads();
  int i = blockIdx.x * 256 + tid;
  if (i < cN_SRC) { int o = excl[i] + ex[i >> 8]; offs[i] = o; cursor[i] = o; }
  else if (i == cN_SRC) offs[cN_SRC] = cE_DOM;
}
// scatter: pre-gather ALL per-edge metadata into CSR position order
__global__ void k_scatter(const int* __restrict__ dme0, const int* __restrict__ dme1,
                          const int* __restrict__ bnd, int* __restrict__ cursor,
                          int4* __restrict__ rec) {
  int e = blockIdx.x * blockDim.x + threadIdx.x;
  if (e < cE_DOM) {
    int t = dme1[e];
    int pos = atomicAdd(&cursor[t], 1);
    int j0 = bnd[e];
    rec[pos] = make_int4(dme0[e], t, j0, bnd[e + 1] - j0);
  }
}

// ---------------- edge kernel (unchanged, verified)
#define EDGE_ISSUE(I, B)                                                     \
  do {                                                                       \
    int le_ = wv * 8 + (I);                                                  \
    int n_ = __builtin_amdgcn_readfirstlane(sR[le_].w);                      \
    _Pragma("unroll")                                                        \
    for (int k_ = 0; k_ < 4; k_++) {                                         \
      int r_ = (k_ < n_) ? __builtin_amdgcn_readlane(idxv[I], k_) : 0;       \
      ub[B][k_] = xwu[(size_t)r_ * 64 + lane];                               \
    }                                                                        \
  } while (0)

#define EDGE_CONSUME(I, B)                                                   \
  do {                                                                       \
    int le_ = wv * 8 + (I);                                                  \
    int j0_ = __builtin_amdgcn_readfirstlane(sR[le_].z);                     \
    int n_ = __builtin_amdgcn_readfirstlane(sR[le_].w);                      \
    float a0_ = 0.f, a1_ = 0.f;                                              \
    _Pragma("unroll")                                                        \
    for (int k_ = 0; k_ < 4; k_++) {                                         \
      unsigned uv_ = (k_ < n_) ? ub[B][k_] : 0u;                             \
      a0_ += bf2f(uv_ & 0xffff);                                             \
      a1_ += bf2f(uv_ >> 16);                                                \
    }                                                                        \
    if (n_ > 4) {                                                            \
      for (int k_ = 4; k_ < n_; k_++) {                                      \
        int r_ = (k_ < 64) ? __builtin_amdgcn_readlane(idxv[I], k_)          \
                           : nme0[j0_ + k_];                                 \
        unsigned uu_ = xwu[(size_t)r_ * 64 + lane];                          \
        a0_ += bf2f(uu_ & 0xffff);                                           \
        a1_ += bf2f(uu_ >> 16);                                              \
      }                                                                      \
    }                                                                        \
    float m0_ = a0_ + bf2f(xs[I] & 0xffff) + bf2f(yy[I] & 0xffff);           \
    float m1_ = a1_ + bf2f(xs[I] >> 16) + bf2f(yy[I] >> 16);                 \
    unsigned um_ = ((unsigned)f2bf(m1_) << 16) | (unsigned)f2bf(m0_);        \
    __builtin_nontemporal_store(um_, &msgu[(size_t)(e0 + le_) * 64 + lane]); \
    s0 += m0_; q0 += m0_ * m0_; s1 += m1_; q1 += m1_ * m1_;                  \
  } while (0)

#define SBAR __builtin_amdgcn_sched_barrier(0)

__global__ __launch_bounds__(256, 8) void k_edge2(
    const unsigned* __restrict__ xwu, const int* __restrict__ nme0,
    const unsigned* __restrict__ xslu, const unsigned* __restrict__ ylu,
    const int4* __restrict__ rec,
    unsigned* __restrict__ msgu, float* __restrict__ part2) {
  __shared__ int4 sR[32];
  __shared__ float sBN[1024];
  int tid = threadIdx.x, lane = tid & 63, wv = tid >> 6;
  int e0 = blockIdx.x * 32;
  if (tid < 32) sR[tid] = rec[e0 + tid];
  __syncthreads();

  unsigned xs[8], yy[8];
  int idxv[8];
#pragma unroll
  for (int i = 0; i < 8; i++) {
    int le = wv * 8 + i;
    int s  = __builtin_amdgcn_readfirstlane(sR[le].x);
    int t  = __builtin_amdgcn_readfirstlane(sR[le].y);
    int j0 = __builtin_amdgcn_readfirstlane(sR[le].z);
    int n  = __builtin_amdgcn_readfirstlane(sR[le].w);
    xs[i] = xslu[(size_t)s * 64 + lane];
    yy[i] = ylu[(size_t)t * 64 + lane];
    idxv[i] = (lane < n) ? nme0[j0 + lane] : 0;
  }
  SBAR;

  float s0 = 0.f, q0 = 0.f, s1 = 0.f, q1 = 0.f;
  unsigned ub[3][4];
  EDGE_ISSUE(0, 0); SBAR;
  EDGE_ISSUE(1, 1); SBAR;
  EDGE_ISSUE(2, 2); SBAR;
  EDGE_CONSUME(0, 0);
  EDGE_ISSUE(3, 0); SBAR;
  EDGE_CONSUME(1, 1);
  EDGE_ISSUE(4, 1); SBAR;
  EDGE_CONSUME(2, 2);
  EDGE_ISSUE(5, 2); SBAR;
  EDGE_CONSUME(3, 0);
  EDGE_ISSUE(6, 0); SBAR;
  EDGE_CONSUME(4, 1);
  EDGE_ISSUE(7, 1); SBAR;
  EDGE_CONSUME(5, 2);
  EDGE_CONSUME(6, 0);
  EDGE_CONSUME(7, 1);

  *(float4*)(&sBN[wv * 256 + lane * 4]) = make_float4(s0, q0, s1, q1);
  __syncthreads();
  float v = sBN[tid] + sBN[256 + tid] + sBN[512 + tid] + sBN[768 + tid];
  atomicAdd(&part2[((blockIdx.x & 63) << 8) + tid], v);
}

// ---------------- BN stat finalize
__global__ __launch_bounds__(256) void k_bnfinal(const float* __restrict__ part2,
                                                 const float* __restrict__ bnw,
                                                 const float* __restrict__ bnb,
                                                 float* __restrict__ ss) {
  __shared__ float L[256];
  float s = 0.f;
  for (int b = 0; b < 64; b++) s += part2[b * 256 + threadIdx.x];
  L[threadIdx.x] = s; __syncthreads();
  if (threadIdx.x < HH) {
    int c = threadIdx.x;
    float sum = L[2 * c], sq = L[2 * c + 1];
    float mean = sum / (float)cE_DOM;
    float var = sq / (float)cE_DOM - mean * mean;
    float sc = bnw[c] * rsqrtf(var + 1e-5f);
    float sh = bnb[c] - mean * sc;
    ss[2 * c] = sc; ss[2 * c + 1] = sh;
  }
}

// ---------------- final reduce (unchanged)
__global__ __launch_bounds__(256, 8) void k_out2(const unsigned* __restrict__ msgu,
                                                 const int* __restrict__ offs,
                                                 const float* __restrict__ ss,
                                                 float* __restrict__ out) {
  int wv = threadIdx.x >> 6, lane = threadIdx.x & 63;
  int t = blockIdx.x * 4 + wv;
  if (t >= cN_Y) return;
  int c0 = lane * 2;
  float sc0 = ss[c0 * 2 + 0], sh0 = ss[c0 * 2 + 1];
  float sc1 = ss[c0 * 2 + 2], sh1 = ss[c0 * 2 + 3];
  int j0 = __builtin_amdgcn_readfirstlane(offs[t]);
  int j1 = __builtin_amdgcn_readfirstlane(offs[t + 1]);
  float a0 = 0.f, a1 = 0.f;
  int p = j0;
  for (; p + 8 <= j1; p += 8) {
    unsigned m[8];
#pragma unroll
    for (int k = 0; k < 8; k++) m[k] = msgu[(size_t)(p + k) * 64 + lane];
    __builtin_amdgcn_sched_barrier(0);
#pragma unroll
    for (int k = 0; k < 8; k++) {
      a0 += fmaxf(fmaf(bf2f(m[k] & 0xffff), sc0, sh0), 0.f);
      a1 += fmaxf(fmaf(bf2f(m[k] >> 16), sc1, sh1), 0.f);
    }
  }
  if (p + 4 <= j1) {
    unsigned m[4];
#pragma unroll
    for (int k = 0; k < 4; k++) m[k] = msgu[(size_t)(p + k) * 64 + lane];
    __builtin_amdgcn_sched_barrier(0);
#pragma unroll
    for (int k = 0; k < 4; k++) {
      a0 += fmaxf(fmaf(bf2f(m[k] & 0xffff), sc0, sh0), 0.f);
      a1 += fmaxf(fmaf(bf2f(m[k] >> 16), sc1, sh1), 0.f);
    }
    p += 4;
  }
  for (; p < j1; p++) {
    unsigned m = msgu[(size_t)p * 64 + lane];
    a0 += fmaxf(fmaf(bf2f(m & 0xffff), sc0, sh0), 0.f);
    a1 += fmaxf(fmaf(bf2f(m >> 16), sc1, sh1), 0.f);
  }
  *(float2*)(out + (size_t)t * HH + c0) = make_float2(a0, a1);
}

extern "C" void kernel_launch(void* const* d_in, const int* in_sizes, int n_in,
                              void* d_out, int out_size, void* d_ws, size_t ws_size,
                              hipStream_t stream) {
  const float* x     = (const float*)d_in[0];
  const float* y     = (const float*)d_in[1];
  const int* dom_ind = (const int*)d_in[2];
  const int* nme     = (const int*)d_in[3];
  const int* ii      = (const int*)d_in[4];
  const int* dme     = (const int*)d_in[5];
  const float* Wxsum = (const float*)d_in[6];
  const float* Wxint = (const float*)d_in[7];
  const float* Wy    = (const float*)d_in[8];
  const float* bnw   = (const float*)d_in[9];
  const float* bnb   = (const float*)d_in[10];
  float* out = (float*)d_out;

  char* ws = (char*)d_ws;
  size_t o = 0;
  auto alloc = [&](size_t bytes) -> void* {
    void* p = ws + o;
    o = (o + bytes + 255) & ~(size_t)255;
    return p;
  };
  float* xsum   = (float*)alloc((size_t)cN_SRC * HH * 4);
  unsigned short* xsl = (unsigned short*)alloc((size_t)cN_SRC * HH * 2);
  unsigned short* ylin = (unsigned short*)alloc((size_t)cN_Y * HH * 2);
  unsigned short* xw = (unsigned short*)alloc((size_t)cN_X * HH * 2);
  unsigned short* msg = (unsigned short*)alloc((size_t)cE_DOM * HH * 2);
  int* bnd      = (int*)alloc((size_t)(cN_INT + 1) * 4);
  int* cnt      = (int*)alloc((size_t)cN_SRC * 4);
  int* excl     = (int*)alloc((size_t)cN_SRC * 4);
  int* bsum     = (int*)alloc(256 * 4);
  int* offs     = (int*)alloc((size_t)(cN_SRC + 1) * 4);
  int* cursor   = (int*)alloc((size_t)cN_SRC * 4);
  int4* rec     = (int4*)alloc((size_t)cE_DOM * 16);
  float* part2  = (float*)alloc(64 * 256 * 4);
  float* ssbuf  = (float*)alloc(256 * 4);

  const int nb_scan = (cN_SRC + 255) / 256;  // 196
  // setup: 782 ylin-gemm + 6250 zero-xsum + 49 zero-cnt + 16 zero-part2 + 3907 bounds
  k_setup<<<782 + 6250 + 49 + 16 + 3907, 256, 0, stream>>>(y, Wy, ylin, ii, bnd,
                                                           xsum, cnt, part2);
  k_gemmx_segsum<<<(cN_X + 63) / 64, 256, 0, stream>>>(x, dom_ind, Wxint, xw, xsum,
                                                       dme + cE_DOM, cnt);
  k_gemmxsl<<<(cN_SRC + 63) / 64, 256, 0, stream>>>(xsum, Wxsum, xsl);
  k_scan1<<<nb_scan, 256, 0, stream>>>(cnt, bsum, excl);
  k_scan23<<<(cN_SRC + 1 + 255) / 256, 256, 0, stream>>>(excl, bsum, offs, cursor, nb_scan);
  k_scatter<<<(cE_DOM + 255) / 256, 256, 0, stream>>>(dme, dme + cE_DOM, bnd, cursor, rec);
  k_edge2<<<cE_DOM / 32, 256, 0, stream>>>((const unsigned*)xw, nme,
                                           (const unsigned*)xsl, (const unsigned*)ylin,
                                           rec, (unsigned*)msg, part2);
  k_bnfinal<<<1, 256, 0, stream>>>(part2, bnw, bnb, ssbuf);
  k_out2<<<(cN_Y + 3) / 4, 256, 0, stream>>>((const unsigned*)msg, offs, ssbuf, out);
}

// Round 8
// 424.224 us; speedup vs baseline: 1.6196x; 1.0419x over previous
//
#include <hip/hip_runtime.h>
#include <cstdint>

#define HH 128
#define SB 136  // padded bf16 LDS row stride for GEMM A tiles (272 B: 16B-aligned, 2-way max bank alias)
constexpr int cN_X   = 250000;
constexpr int cN_SRC = 50000;
constexpr int cN_Y   = 50000;
constexpr int cN_INT = 500000;
constexpr int cE_NODE = 1000000;
constexpr int cE_DOM  = 500000;

typedef __attribute__((ext_vector_type(8))) short bf16x8;
typedef __attribute__((ext_vector_type(4))) float f32x4;

__device__ __forceinline__ float bf2f(unsigned short s) {
  union { unsigned u; float f; } v; v.u = ((unsigned)s) << 16; return v.f;
}
__device__ __forceinline__ unsigned short f2bf(float f) {
  union { float f; unsigned u; } v; v.f = f;
  unsigned r = v.u + 0x7fffu + ((v.u >> 16) & 1u);  // RNE
  return (unsigned short)(r >> 16);
}

// ---------------- MFMA helpers (bf16 precomputed weights)
__device__ __forceinline__ void load_bfrags(const unsigned short* __restrict__ Wbf,
                                            int wv, int lane, bf16x8 bfrag[2][4]) {
  int cbase = wv * 32 + (lane & 15);
  int krow = (lane >> 4) * 8;
#pragma unroll
  for (int ct = 0; ct < 2; ct++)
#pragma unroll
    for (int kt = 0; kt < 4; kt++)
      bfrag[ct][kt] = *(const bf16x8*)(Wbf + (size_t)(cbase + ct * 16) * HH + kt * 32 + krow);
}

// shared GEMM tile body: outb[row0..row0+rows][128](bf16) = A @ W^T (W bf16)
__device__ __forceinline__ void gemm_tile(const float* __restrict__ A,
                                          const unsigned short* __restrict__ Wbf,
                                          unsigned short* __restrict__ outb,
                                          int row0, int rows,
                                          unsigned short* sA, int tid) {
  int lane = tid & 63, wv = tid >> 6;
  bf16x8 bfrag[2][4];
  load_bfrags(Wbf, wv, lane, bfrag);
#pragma unroll
  for (int it = 0; it < 4; it++) {
    int g = it * 2048 + tid * 8;
    int r = g >> 7, c = g & 127;
    bf16x8 v = {0, 0, 0, 0, 0, 0, 0, 0};
    if (r < rows) {
      float4 f0 = *(const float4*)(A + (size_t)(row0 + r) * HH + c);
      float4 f1 = *(const float4*)(A + (size_t)(row0 + r) * HH + c + 4);
      v[0] = (short)f2bf(f0.x); v[1] = (short)f2bf(f0.y);
      v[2] = (short)f2bf(f0.z); v[3] = (short)f2bf(f0.w);
      v[4] = (short)f2bf(f1.x); v[5] = (short)f2bf(f1.y);
      v[6] = (short)f2bf(f1.z); v[7] = (short)f2bf(f1.w);
    }
    *(bf16x8*)(&sA[r * SB + c]) = v;
  }
  __syncthreads();
  int m = lane & 15, q = lane >> 4;
  f32x4 acc[4][2];
#pragma unroll
  for (int rt = 0; rt < 4; rt++)
#pragma unroll
    for (int ct = 0; ct < 2; ct++) acc[rt][ct] = (f32x4){0.f, 0.f, 0.f, 0.f};
#pragma unroll
  for (int kt = 0; kt < 4; kt++) {
    int kof = kt * 32 + q * 8;
#pragma unroll
    for (int rt = 0; rt < 4; rt++) {
      bf16x8 af = *(const bf16x8*)(&sA[(rt * 16 + m) * SB + kof]);
      acc[rt][0] = __builtin_amdgcn_mfma_f32_16x16x32_bf16(af, bfrag[0][kt], acc[rt][0], 0, 0, 0);
      acc[rt][1] = __builtin_amdgcn_mfma_f32_16x16x32_bf16(af, bfrag[1][kt], acc[rt][1], 0, 0, 0);
    }
  }
  __syncthreads();
  unsigned short* sC = sA;
#pragma unroll
  for (int rt = 0; rt < 4; rt++)
#pragma unroll
    for (int ct = 0; ct < 2; ct++)
#pragma unroll
      for (int rg = 0; rg < 4; rg++) {
        int r = rt * 16 + q * 4 + rg;
        sC[r * HH + wv * 32 + ct * 16 + m] = f2bf(acc[rt][ct][rg]);
      }
  __syncthreads();
  for (int i = tid; i < rows * 16; i += 256) {
    int r = i >> 4, g = i & 15;
    ((uint4*)(outb + (size_t)(row0 + r) * HH))[g] = ((const uint4*)(sC + r * HH))[g];
  }
}

// ---------------- setup mega-kernel: wcast + zero(xsum,cnt,part2) + bounds.
// All regions mutually independent; consumers are in LATER dispatches.
// blocks: [0,48) wcast | [48,6298) zero xsum | [6298,6347) zero cnt |
//         [6347,6363) zero part2 | [6363,10270) bounds
__global__ __launch_bounds__(256) void k_setup(const float* __restrict__ w0,
                                               const float* __restrict__ w1,
                                               const float* __restrict__ w2,
                                               unsigned short* __restrict__ dst,
                                               const int* __restrict__ ii,
                                               int* __restrict__ bnd,
                                               float* __restrict__ xsum,
                                               int* __restrict__ cnt,
                                               float* __restrict__ part2) {
  int b = blockIdx.x, tid = threadIdx.x;
  if (b < 48) {  // wcast: 3 x 128x128 f32 -> bf16 (Wxsum@0, Wy@16384, Wxint@32768)
    int i = b * 256 + tid;
    int idx4 = i * 4;
    int mat = idx4 >> 14;
    int off = idx4 & 16383;
    const float* src = (mat == 0) ? w0 : (mat == 1) ? w1 : w2;
    float4 v = *(const float4*)(src + off);
    ushort4 u;
    u.x = f2bf(v.x); u.y = f2bf(v.y); u.z = f2bf(v.z); u.w = f2bf(v.w);
    *(ushort4*)(dst + (size_t)mat * 16384 + off) = u;
    return;
  }
  b -= 48;
  if (b < 6250) {  // zero xsum: 6.4M floats = 1.6M float4
    ((float4*)xsum)[(size_t)b * 256 + tid] = make_float4(0.f, 0.f, 0.f, 0.f);
    return;
  }
  b -= 6250;
  if (b < 49) {  // zero cnt: 50000 ints = 12500 int4
    int i = b * 256 + tid;
    if (i < 12500) ((int4*)cnt)[i] = make_int4(0, 0, 0, 0);
    return;
  }
  b -= 49;
  if (b < 16) {  // zero part2: 16384 floats = 4096 float4
    ((float4*)part2)[b * 256 + tid] = make_float4(0.f, 0.f, 0.f, 0.f);
    return;
  }
  b -= 16;
  {  // bounds: bnd[e] = first j with ii[j] >= e
    int j = b * 256 + tid;
    if (j > cE_NODE) return;
    if (j == cE_NODE) {
      int a = ii[cE_NODE - 1];
      for (int e = a + 1; e <= cN_INT; ++e) bnd[e] = cE_NODE;
      return;
    }
    int bb = ii[j];
    int a = (j == 0) ? -1 : ii[j - 1];
    for (int e = a + 1; e <= bb; ++e) bnd[e] = j;
  }
}

// ---------------- fused: xw = x @ Wxint^T (bf16 W) + segsum(x) + dme1 hist.
__global__ __launch_bounds__(256, 4) void k_gemmx_segsum(
    const float* __restrict__ A, const int* __restrict__ ind,
    const unsigned short* __restrict__ Wbf,
    unsigned short* __restrict__ outb, float* __restrict__ xsum,
    const int* __restrict__ dme1, int* __restrict__ cnt) {
  __shared__ unsigned short sA[64 * SB];
  __shared__ int sind[64];
  int tid = threadIdx.x, lane = tid & 63, wv = tid >> 6;
  {  // fused histogram of dme1 (grid 3907 x 256 covers 500K with guard)
    int e = blockIdx.x * 256 + tid;
    if (e < cE_DOM) atomicAdd(&cnt[dme1[e]], 1);
  }
  int row0 = blockIdx.x * 64;
  int rows = min(64, cN_X - row0);
  if (tid < 64 && tid < rows) sind[tid] = ind[row0 + tid];
  bf16x8 bfrag[2][4];
  load_bfrags(Wbf, wv, lane, bfrag);
  // stage 64x128 f32 -> bf16 LDS
#pragma unroll
  for (int it = 0; it < 4; it++) {
    int g = it * 2048 + tid * 8;
    int r = g >> 7, c = g & 127;
    bf16x8 v = {0, 0, 0, 0, 0, 0, 0, 0};
    if (r < rows) {
      float4 f0 = *(const float4*)(A + (size_t)(row0 + r) * HH + c);
      float4 f1 = *(const float4*)(A + (size_t)(row0 + r) * HH + c + 4);
      v[0] = (short)f2bf(f0.x); v[1] = (short)f2bf(f0.y);
      v[2] = (short)f2bf(f0.z); v[3] = (short)f2bf(f0.w);
      v[4] = (short)f2bf(f1.x); v[5] = (short)f2bf(f1.y);
      v[6] = (short)f2bf(f1.z); v[7] = (short)f2bf(f1.w);
    }
    *(bf16x8*)(&sA[r * SB + c]) = v;
  }
  __syncthreads();
  // ---- segment-sum side: wave wv owns rows [wv*16, wv*16+16), lane = col pair
  {
    int rbase = wv * 16;
    if (rbase < rows) {
      int nr = min(16, rows - rbase);
      int c0 = lane * 2;
      unsigned xv[16];
#pragma unroll
      for (int k = 0; k < 16; k++)
        xv[k] = (k < nr) ? *(const unsigned*)(&sA[(rbase + k) * SB + c0]) : 0u;
      float a0 = 0.f, a1 = 0.f;
      int cur = sind[rbase];
      bool inside = false;
#pragma unroll
      for (int k = 0; k < 16; k++) {
        if (k < nr) {
          int s = sind[rbase + k];
          if (s != cur) {
            if (inside) {
              xsum[(size_t)cur * HH + c0] = a0;
              xsum[(size_t)cur * HH + c0 + 1] = a1;
            } else {
              atomicAdd(&xsum[(size_t)cur * HH + c0], a0);
              atomicAdd(&xsum[(size_t)cur * HH + c0 + 1], a1);
            }
            cur = s; a0 = 0.f; a1 = 0.f; inside = true;
          }
          a0 += bf2f(xv[k] & 0xffff); a1 += bf2f(xv[k] >> 16);
        }
      }
      atomicAdd(&xsum[(size_t)cur * HH + c0], a0);
      atomicAdd(&xsum[(size_t)cur * HH + c0 + 1], a1);
    }
  }
  // ---- MFMA side
  int m = lane & 15, q = lane >> 4;
  f32x4 acc[4][2];
#pragma unroll
  for (int rt = 0; rt < 4; rt++)
#pragma unroll
    for (int ct = 0; ct < 2; ct++) acc[rt][ct] = (f32x4){0.f, 0.f, 0.f, 0.f};
#pragma unroll
  for (int kt = 0; kt < 4; kt++) {
    int kof = kt * 32 + q * 8;
#pragma unroll
    for (int rt = 0; rt < 4; rt++) {
      bf16x8 af = *(const bf16x8*)(&sA[(rt * 16 + m) * SB + kof]);
      acc[rt][0] = __builtin_amdgcn_mfma_f32_16x16x32_bf16(af, bfrag[0][kt], acc[rt][0], 0, 0, 0);
      acc[rt][1] = __builtin_amdgcn_mfma_f32_16x16x32_bf16(af, bfrag[1][kt], acc[rt][1], 0, 0, 0);
    }
  }
  __syncthreads();
  unsigned short* sC = sA;
#pragma unroll
  for (int rt = 0; rt < 4; rt++)
#pragma unroll
    for (int ct = 0; ct < 2; ct++)
#pragma unroll
      for (int rg = 0; rg < 4; rg++) {
        int r = rt * 16 + q * 4 + rg;
        sC[r * HH + wv * 32 + ct * 16 + m] = f2bf(acc[rt][ct][rg]);
      }
  __syncthreads();
  for (int i = tid; i < rows * 16; i += 256) {
    int r = i >> 4, g = i & 15;
    ((uint4*)(outb + (size_t)(row0 + r) * HH))[g] = ((const uint4*)(sC + r * HH))[g];
  }
}

// ---------------- both 50K-row GEMMs + scan1 region in ONE launch:
// blocks [0,782) -> xsl | [782,1564) -> ylin | [1564,1760) -> scan1.
// scan1 is safe here: cnt completed in the PRIOR dispatch (gemmx_segsum's
// hist); scan1's consumer (scan23) is a LATER dispatch.
__global__ __launch_bounds__(256, 4) void k_gemm2(const float* __restrict__ Axs,
                                                  const float* __restrict__ Ay,
                                                  const unsigned short* __restrict__ Wbf,
                                                  unsigned short* __restrict__ xsl,
                                                  unsigned short* __restrict__ ylin,
                                                  const int* __restrict__ cnt,
                                                  int* __restrict__ bsum,
                                                  int* __restrict__ excl) {
  __shared__ unsigned short sA[64 * SB];
  __shared__ int buf[256];
  int tid = threadIdx.x;
  const int nbm = (cN_SRC + 63) / 64;  // 782
  if (blockIdx.x >= 2 * nbm) {  // scan1 region
    int sb = blockIdx.x - 2 * nbm;
    int i = sb * 256 + tid;
    int v = (i < cN_SRC) ? cnt[i] : 0;
    buf[tid] = v; __syncthreads();
    for (int d = 1; d < 256; d <<= 1) {
      int t = (tid >= d) ? buf[tid - d] : 0;
      __syncthreads();
      buf[tid] += t;
      __syncthreads();
    }
    if (i < cN_SRC) excl[i] = buf[tid] - v;
    if (tid == 255) bsum[sb] = buf[255];
    return;
  }
  bool isY = blockIdx.x >= nbm;
  const float* A = isY ? Ay : Axs;
  const unsigned short* W = Wbf + (isY ? 16384 : 0);
  unsigned short* outb = isY ? ylin : xsl;
  int bb = isY ? blockIdx.x - nbm : blockIdx.x;
  int row0 = bb * 64;
  int rows = min(64, cN_SRC - row0);
  gemm_tile(A, W, outb, row0, rows, sA, tid);
}

// ---------------- scan2+scan3 fused
__global__ __launch_bounds__(256) void k_scan23(const int* __restrict__ excl,
                                                const int* __restrict__ bsum,
                                                int* __restrict__ offs,
                                                int* __restrict__ cursor, int nb) {
  __shared__ int buf[256];
  __shared__ int ex[256];
  int tid = threadIdx.x;
  int v = (tid < nb) ? bsum[tid] : 0;
  buf[tid] = v; __syncthreads();
  for (int d = 1; d < 256; d <<= 1) {
    int t = (tid >= d) ? buf[tid - d] : 0;
    __syncthreads();
    buf[tid] += t;
    __syncthreads();
  }
  ex[tid] = buf[tid] - v;
  __syncthreads();
  int i = blockIdx.x * 256 + tid;
  if (i < cN_SRC) { int o = excl[i] + ex[i >> 8]; offs[i] = o; cursor[i] = o; }
  else if (i == cN_SRC) offs[cN_SRC] = cE_DOM;
}
// scatter: pre-gather ALL per-edge metadata into CSR position order
__global__ void k_scatter(const int* __restrict__ dme0, const int* __restrict__ dme1,
                          const int* __restrict__ bnd, int* __restrict__ cursor,
                          int4* __restrict__ rec) {
  int e = blockIdx.x * blockDim.x + threadIdx.x;
  if (e < cE_DOM) {
    int t = dme1[e];
    int pos = atomicAdd(&cursor[t], 1);
    int j0 = bnd[e];
    rec[pos] = make_int4(dme0[e], t, j0, bnd[e + 1] - j0);
  }
}

// ---------------- edge kernel (unchanged, verified)
#define EDGE_ISSUE(I, B)                                                     \
  do {                                                                       \
    int le_ = wv * 8 + (I);                                                  \
    int n_ = __builtin_amdgcn_readfirstlane(sR[le_].w);                      \
    _Pragma("unroll")                                                        \
    for (int k_ = 0; k_ < 4; k_++) {                                         \
      int r_ = (k_ < n_) ? __builtin_amdgcn_readlane(idxv[I], k_) : 0;       \
      ub[B][k_] = xwu[(size_t)r_ * 64 + lane];                               \
    }                                                                        \
  } while (0)

#define EDGE_CONSUME(I, B)                                                   \
  do {                                                                       \
    int le_ = wv * 8 + (I);                                                  \
    int j0_ = __builtin_amdgcn_readfirstlane(sR[le_].z);                     \
    int n_ = __builtin_amdgcn_readfirstlane(sR[le_].w);                      \
    float a0_ = 0.f, a1_ = 0.f;                                              \
    _Pragma("unroll")                                                        \
    for (int k_ = 0; k_ < 4; k_++) {                                         \
      unsigned uv_ = (k_ < n_) ? ub[B][k_] : 0u;                             \
      a0_ += bf2f(uv_ & 0xffff);                                             \
      a1_ += bf2f(uv_ >> 16);                                                \
    }                                                                        \
    if (n_ > 4) {                                                            \
      for (int k_ = 4; k_ < n_; k_++) {                                      \
        int r_ = (k_ < 64) ? __builtin_amdgcn_readlane(idxv[I], k_)          \
                           : nme0[j0_ + k_];                                 \
        unsigned uu_ = xwu[(size_t)r_ * 64 + lane];                          \
        a0_ += bf2f(uu_ & 0xffff);                                           \
        a1_ += bf2f(uu_ >> 16);                                              \
      }                                                                      \
    }                                                                        \
    float m0_ = a0_ + bf2f(xs[I] & 0xffff) + bf2f(yy[I] & 0xffff);           \
    float m1_ = a1_ + bf2f(xs[I] >> 16) + bf2f(yy[I] >> 16);                 \
    unsigned um_ = ((unsigned)f2bf(m1_) << 16) | (unsigned)f2bf(m0_);        \
    __builtin_nontemporal_store(um_, &msgu[(size_t)(e0 + le_) * 64 + lane]); \
    s0 += m0_; q0 += m0_ * m0_; s1 += m1_; q1 += m1_ * m1_;                  \
  } while (0)

#define SBAR __builtin_amdgcn_sched_barrier(0)

__global__ __launch_bounds__(256, 8) void k_edge2(
    const unsigned* __restrict__ xwu, const int* __restrict__ nme0,
    const unsigned* __restrict__ xslu, const unsigned* __restrict__ ylu,
    const int4* __restrict__ rec,
    unsigned* __restrict__ msgu, float* __restrict__ part2) {
  __shared__ int4 sR[32];
  __shared__ float sBN[1024];
  int tid = threadIdx.x, lane = tid & 63, wv = tid >> 6;
  int e0 = blockIdx.x * 32;
  if (tid < 32) sR[tid] = rec[e0 + tid];
  __syncthreads();

  unsigned xs[8], yy[8];
  int idxv[8];
#pragma unroll
  for (int i = 0; i < 8; i++) {
    int le = wv * 8 + i;
    int s  = __builtin_amdgcn_readfirstlane(sR[le].x);
    int t  = __builtin_amdgcn_readfirstlane(sR[le].y);
    int j0 = __builtin_amdgcn_readfirstlane(sR[le].z);
    int n  = __builtin_amdgcn_readfirstlane(sR[le].w);
    xs[i] = xslu[(size_t)s * 64 + lane];
    yy[i] = ylu[(size_t)t * 64 + lane];
    idxv[i] = (lane < n) ? nme0[j0 + lane] : 0;
  }
  SBAR;

  float s0 = 0.f, q0 = 0.f, s1 = 0.f, q1 = 0.f;
  unsigned ub[3][4];
  EDGE_ISSUE(0, 0); SBAR;
  EDGE_ISSUE(1, 1); SBAR;
  EDGE_ISSUE(2, 2); SBAR;
  EDGE_CONSUME(0, 0);
  EDGE_ISSUE(3, 0); SBAR;
  EDGE_CONSUME(1, 1);
  EDGE_ISSUE(4, 1); SBAR;
  EDGE_CONSUME(2, 2);
  EDGE_ISSUE(5, 2); SBAR;
  EDGE_CONSUME(3, 0);
  EDGE_ISSUE(6, 0); SBAR;
  EDGE_CONSUME(4, 1);
  EDGE_ISSUE(7, 1); SBAR;
  EDGE_CONSUME(5, 2);
  EDGE_CONSUME(6, 0);
  EDGE_CONSUME(7, 1);

  *(float4*)(&sBN[wv * 256 + lane * 4]) = make_float4(s0, q0, s1, q1);
  __syncthreads();
  float v = sBN[tid] + sBN[256 + tid] + sBN[512 + tid] + sBN[768 + tid];
  atomicAdd(&part2[((blockIdx.x & 63) << 8) + tid], v);
}

// ---------------- BN stat finalize
__global__ __launch_bounds__(256) void k_bnfinal(const float* __restrict__ part2,
                                                 const float* __restrict__ bnw,
                                                 const float* __restrict__ bnb,
                                                 float* __restrict__ ss) {
  __shared__ float L[256];
  float s = 0.f;
  for (int b = 0; b < 64; b++) s += part2[b * 256 + threadIdx.x];
  L[threadIdx.x] = s; __syncthreads();
  if (threadIdx.x < HH) {
    int c = threadIdx.x;
    float sum = L[2 * c], sq = L[2 * c + 1];
    float mean = sum / (float)cE_DOM;
    float var = sq / (float)cE_DOM - mean * mean;
    float sc = bnw[c] * rsqrtf(var + 1e-5f);
    float sh = bnb[c] - mean * sc;
    ss[2 * c] = sc; ss[2 * c + 1] = sh;
  }
}

// ---------------- final reduce (unchanged)
__global__ __launch_bounds__(256, 8) void k_out2(const unsigned* __restrict__ msgu,
                                                 const int* __restrict__ offs,
                                                 const float* __restrict__ ss,
                                                 float* __restrict__ out) {
  int wv = threadIdx.x >> 6, lane = threadIdx.x & 63;
  int t = blockIdx.x * 4 + wv;
  if (t >= cN_Y) return;
  int c0 = lane * 2;
  float sc0 = ss[c0 * 2 + 0], sh0 = ss[c0 * 2 + 1];
  float sc1 = ss[c0 * 2 + 2], sh1 = ss[c0 * 2 + 3];
  int j0 = __builtin_amdgcn_readfirstlane(offs[t]);
  int j1 = __builtin_amdgcn_readfirstlane(offs[t + 1]);
  float a0 = 0.f, a1 = 0.f;
  int p = j0;
  for (; p + 8 <= j1; p += 8) {
    unsigned m[8];
#pragma unroll
    for (int k = 0; k < 8; k++) m[k] = msgu[(size_t)(p + k) * 64 + lane];
    __builtin_amdgcn_sched_barrier(0);
#pragma unroll
    for (int k = 0; k < 8; k++) {
      a0 += fmaxf(fmaf(bf2f(m[k] & 0xffff), sc0, sh0), 0.f);
      a1 += fmaxf(fmaf(bf2f(m[k] >> 16), sc1, sh1), 0.f);
    }
  }
  if (p + 4 <= j1) {
    unsigned m[4];
#pragma unroll
    for (int k = 0; k < 4; k++) m[k] = msgu[(size_t)(p + k) * 64 + lane];
    __builtin_amdgcn_sched_barrier(0);
#pragma unroll
    for (int k = 0; k < 4; k++) {
      a0 += fmaxf(fmaf(bf2f(m[k] & 0xffff), sc0, sh0), 0.f);
      a1 += fmaxf(fmaf(bf2f(m[k] >> 16), sc1, sh1), 0.f);
    }
    p += 4;
  }
  for (; p < j1; p++) {
    unsigned m = msgu[(size_t)p * 64 + lane];
    a0 += fmaxf(fmaf(bf2f(m & 0xffff), sc0, sh0), 0.f);
    a1 += fmaxf(fmaf(bf2f(m >> 16), sc1, sh1), 0.f);
  }
  *(float2*)(out + (size_t)t * HH + c0) = make_float2(a0, a1);
}

extern "C" void kernel_launch(void* const* d_in, const int* in_sizes, int n_in,
                              void* d_out, int out_size, void* d_ws, size_t ws_size,
                              hipStream_t stream) {
  const float* x     = (const float*)d_in[0];
  const float* y     = (const float*)d_in[1];
  const int* dom_ind = (const int*)d_in[2];
  const int* nme     = (const int*)d_in[3];
  const int* ii      = (const int*)d_in[4];
  const int* dme     = (const int*)d_in[5];
  const float* Wxsum = (const float*)d_in[6];
  const float* Wxint = (const float*)d_in[7];
  const float* Wy    = (const float*)d_in[8];
  const float* bnw   = (const float*)d_in[9];
  const float* bnb   = (const float*)d_in[10];
  float* out = (float*)d_out;

  char* ws = (char*)d_ws;
  size_t o = 0;
  auto alloc = [&](size_t bytes) -> void* {
    void* p = ws + o;
    o = (o + bytes + 255) & ~(size_t)255;
    return p;
  };
  float* xsum   = (float*)alloc((size_t)cN_SRC * HH * 4);
  unsigned short* xsl = (unsigned short*)alloc((size_t)cN_SRC * HH * 2);
  unsigned short* ylin = (unsigned short*)alloc((size_t)cN_Y * HH * 2);
  unsigned short* xw = (unsigned short*)alloc((size_t)cN_X * HH * 2);
  unsigned short* msg = (unsigned short*)alloc((size_t)cE_DOM * HH * 2);
  int* bnd      = (int*)alloc((size_t)(cN_INT + 1) * 4);
  int* cnt      = (int*)alloc((size_t)cN_SRC * 4);
  int* excl     = (int*)alloc((size_t)cN_SRC * 4);
  int* bsum     = (int*)alloc(256 * 4);
  int* offs     = (int*)alloc((size_t)(cN_SRC + 1) * 4);
  int* cursor   = (int*)alloc((size_t)cN_SRC * 4);
  int4* rec     = (int4*)alloc((size_t)cE_DOM * 16);
  float* part2  = (float*)alloc(64 * 256 * 4);
  float* ssbuf  = (float*)alloc(256 * 4);
  unsigned short* Wbf = (unsigned short*)alloc(3 * 16384 * 2);

  const int nb_scan = (cN_SRC + 255) / 256;  // 196
  const int nbm = (cN_SRC + 63) / 64;        // 782
  // setup: 48 wcast + 6250 zero-xsum + 49 zero-cnt + 16 zero-part2 + 3907 bounds
  k_setup<<<48 + 6250 + 49 + 16 + 3907, 256, 0, stream>>>(Wxsum, Wy, Wxint, Wbf,
                                                          ii, bnd, xsum, cnt, part2);
  k_gemmx_segsum<<<(cN_X + 63) / 64, 256, 0, stream>>>(x, dom_ind, Wbf + 32768, xw, xsum,
                                                       dme + cE_DOM, cnt);
  k_gemm2<<<2 * nbm + nb_scan, 256, 0, stream>>>(xsum, y, Wbf, xsl, ylin,
                                                 cnt, bsum, excl);
  k_scan23<<<(cN_SRC + 1 + 255) / 256, 256, 0, stream>>>(excl, bsum, offs, cursor, nb_scan);
  k_scatter<<<(cE_DOM + 255) / 256, 256, 0, stream>>>(dme, dme + cE_DOM, bnd, cursor, rec);
  k_edge2<<<cE_DOM / 32, 256, 0, stream>>>((const unsigned*)xw, nme,
                                           (const unsigned*)xsl, (const unsigned*)ylin,
                                           rec, (unsigned*)msg, part2);
  k_bnfinal<<<1, 256, 0, stream>>>(part2, bnw, bnb, ssbuf);
  k_out2<<<(cN_Y + 3) / 4, 256, 0, stream>>>((const unsigned*)msg, offs, ssbuf, out);
}